// Round 3
// baseline (680.868 us; speedup 1.0000x reference)
//
#include <hip/hip_runtime.h>
#include <hip/hip_bf16.h>
#include <stdint.h>

constexpr int A_ = 8, B_ = 32768, O_ = 256, C_ = 64, F_ = 320, E_ = 128;
constexpr int NCH = 128, CHROWS = B_ / NCH;
constexpr int NBT = B_ / 16;   // 2048 batch tiles of 16
constexpr int KA = 11;         // stageA k-steps: 320 + bias-aug 32
constexpr int K1 = 9;          // f1: 256 + aug
constexpr int K2 = 5;          // f2: 128 + aug

typedef __attribute__((ext_vector_type(8))) __bf16 bf16x8;
typedef __attribute__((ext_vector_type(4))) float f32x4;

__device__ __forceinline__ float lrelu(float x){ return x >= 0.f ? x : 0.01f * x; }
__device__ __forceinline__ f32x4 lrelu4(f32x4 x){
  f32x4 r; r[0]=lrelu(x[0]); r[1]=lrelu(x[1]); r[2]=lrelu(x[2]); r[3]=lrelu(x[3]); return r;
}
__device__ __forceinline__ f32x4 mfma16(bf16x8 a, bf16x8 b, f32x4 c){
  return __builtin_amdgcn_mfma_f32_16x16x32_bf16(a, b, c, 0, 0, 0);
}
__device__ __forceinline__ uint2 pk4(f32x4 x){
  union { __bf16 b[4]; uint2 u; } r;
  r.b[0]=(__bf16)x[0]; r.b[1]=(__bf16)x[1]; r.b[2]=(__bf16)x[2]; r.b[3]=(__bf16)x[3];
  return r.u;
}
__device__ __forceinline__ bf16x8 pk8(f32x4 lo, f32x4 hi){
  union { __bf16 b[8]; bf16x8 v; } r;
  r.b[0]=(__bf16)lo[0]; r.b[1]=(__bf16)lo[1]; r.b[2]=(__bf16)lo[2]; r.b[3]=(__bf16)lo[3];
  r.b[4]=(__bf16)hi[0]; r.b[5]=(__bf16)hi[1]; r.b[6]=(__bf16)hi[2]; r.b[7]=(__bf16)hi[3];
  return r.v;
}
__device__ __forceinline__ bf16x8 cat2(uint2 lo, uint2 hi){
  union { uint2 u[2]; bf16x8 v; } r; r.u[0]=lo; r.u[1]=hi; return r.v;
}
__device__ __forceinline__ f32x4 sub4(float4 s, uint2 v){
  union { uint2 q; __bf16 b[4]; } c; c.q = v;
  f32x4 r; r[0]=s.x-(float)c.b[0]; r[1]=s.y-(float)c.b[1];
  r[2]=s.z-(float)c.b[2]; r[3]=s.w-(float)c.b[3]; return r;
}
__device__ __forceinline__ bf16x8 pkz(float4 x0, float4 x1, float4 s0, float4 s1,
                                      float4 h0, float4 h1){
  bf16x8 r;
  r[0]=(__bf16)fmaf(x0.x,s0.x,h0.x); r[1]=(__bf16)fmaf(x0.y,s0.y,h0.y);
  r[2]=(__bf16)fmaf(x0.z,s0.z,h0.z); r[3]=(__bf16)fmaf(x0.w,s0.w,h0.w);
  r[4]=(__bf16)fmaf(x1.x,s1.x,h1.x); r[5]=(__bf16)fmaf(x1.y,s1.y,h1.y);
  r[6]=(__bf16)fmaf(x1.z,s1.z,h1.z); r[7]=(__bf16)fmaf(x1.w,s1.w,h1.w);
  return r;
}

// ---------------- Stage 0: BN stats ----------------
__global__ void k_stats_partial(const float* __restrict__ obs,
                                const float* __restrict__ act,
                                float* __restrict__ psum, float* __restrict__ psq){
  const int f = threadIdx.x, ch = blockIdx.x, a = blockIdx.y;
  const size_t b0 = (size_t)ch * CHROWS;
  float s = 0.f, q = 0.f;
  if (f < O_){
    const float* p = obs + ((size_t)a*B_ + b0)*O_ + f;
    for (int i = 0; i < CHROWS; ++i){ float x = p[(size_t)i*O_]; s += x; q += x*x; }
  } else {
    const float* p = act + ((size_t)a*B_ + b0)*C_ + (f - O_);
    for (int i = 0; i < CHROWS; ++i){ float x = p[(size_t)i*C_]; s += x; q += x*x; }
  }
  psum[((size_t)a*NCH + ch)*F_ + f] = s;
  psq [((size_t)a*NCH + ch)*F_ + f] = q;
}

__global__ void k_stats_final(const float* __restrict__ psum, const float* __restrict__ psq,
                              float* __restrict__ zscale, float* __restrict__ zshift){
  const int f = threadIdx.x, a = blockIdx.x;
  float s = 0.f, q = 0.f;
  for (int ch = 0; ch < NCH; ++ch){
    s += psum[((size_t)a*NCH + ch)*F_ + f];
    q += psq [((size_t)a*NCH + ch)*F_ + f];
  }
  const float mean = s * (1.0f / B_);
  float var = q * (1.0f / B_) - mean * mean;
  var = fmaxf(var, 0.0f);
  const float rs = rsqrtf(var + 1e-5f);
  zscale[a*F_ + f] = rs;
  zshift[a*F_ + f] = -mean * rs;
}

// ---- pack weights as MFMA A-fragments (weights are the A operand everywhere) ----
// Ap : natural k-map (z is built natural), k-aug bias column at k=320.
// B1p/B2p/Vp : pi k-map  f = 32*ks + 16*(e>>2) + 4*lg + (e&3)  (+ aug k-step).
__global__ void k_prep(const float* __restrict__ gW, const float* __restrict__ gb,
                       const float* __restrict__ ggam, const float* __restrict__ gbet,
                       const float* __restrict__ sW, const float* __restrict__ sb,
                       const float* __restrict__ sgam, const float* __restrict__ sbet,
                       const float* __restrict__ f1W, const float* __restrict__ f1b,
                       const float* __restrict__ f2W, const float* __restrict__ f2b,
                       const float* __restrict__ Vm,
                       __bf16* __restrict__ Ap, __bf16* __restrict__ Vp,
                       __bf16* __restrict__ B1p, __bf16* __restrict__ B2p,
                       float* __restrict__ gbp, float* __restrict__ sbp){
  const int a = blockIdx.x, t = threadIdx.x;
  if (t < E_){
    float ag = gb[a*E_ + t];
    for (int f = 0; f < F_; ++f) ag += gbet[a*F_ + f] * gW[(size_t)a*E_*F_ + (size_t)t*F_ + f];
    gbp[a*E_ + t] = ag;
    float as = sb[a*E_ + t];
    for (int f = 0; f < O_; ++f) as += sbet[a*O_ + f] * sW[(size_t)a*E_*O_ + (size_t)t*O_ + f];
    sbp[a*E_ + t] = as;
  }
  __syncthreads();
  // Ap: [ks 0..10][mO 0..15][l][e], natural k = 32ks + 8lg + e
  for (int i = t; i < KA*16*64*8; i += 256){
    const int ks = i >> 13, mO = (i>>9)&15, l = (i>>3)&63, e = i&7;
    const int r = l&15, lg = l>>4;
    const int fo = mO*16 + r, k = ks*32 + lg*8 + e;
    float v;
    if (k < F_){
      if (fo < 128) v = gW[(size_t)a*E_*F_ + (size_t)fo*F_ + k] * ggam[a*F_ + k];
      else          v = (k < O_) ? sW[(size_t)a*E_*O_ + (size_t)(fo-128)*O_ + k] * sgam[a*O_ + k] : 0.f;
    } else if (k == F_){
      v = (fo < 128) ? gbp[a*E_ + fo] : sbp[a*E_ + fo - 128];
    } else v = 0.f;
    Ap[(size_t)a*(KA*16*64*8) + i] = (__bf16)v;
  }
  // B1p: [ks 0..8][mH 0..7][l][e], pi map; ks=8 bias
  for (int i = t; i < K1*8*64*8; i += 256){
    const int ks = i >> 12, mH = (i>>9)&7, l = (i>>3)&63, e = i&7;
    const int r = l&15, lg = l>>4;
    const int h = mH*16 + r;
    float v;
    if (ks < 8){
      const int f = 32*ks + 16*(e>>2) + 4*lg + (e&3);
      v = f1W[(size_t)a*E_*2*E_ + (size_t)h*2*E_ + f];
    } else v = (lg==0 && e==0) ? f1b[a*E_ + h] : 0.f;
    B1p[(size_t)a*(K1*8*64*8) + i] = (__bf16)v;
  }
  // B2p: [ks 0..4][mC 0..3][l][e]
  for (int i = t; i < K2*4*64*8; i += 256){
    const int ks = i >> 11, mC = (i>>9)&3, l = (i>>3)&63, e = i&7;
    const int r = l&15, lg = l>>4;
    const int c = mC*16 + r;
    float v;
    if (ks < 4){
      const int f = 32*ks + 16*(e>>2) + 4*lg + (e&3);
      v = f2W[(size_t)a*C_*E_ + (size_t)c*E_ + f];
    } else v = (lg==0 && e==0) ? f2b[a*C_ + c] : 0.f;
    B2p[(size_t)a*(K2*4*64*8) + i] = (__bf16)v;
  }
  // Vp: [ks 0..3][mV 0..7][l][e], shared
  if (a == 0){
    for (int i = t; i < 4*8*64*8; i += 256){
      const int ks = i >> 12, mV = (i>>9)&7, l = (i>>3)&63, e = i&7;
      const int r = l&15, lg = l>>4;
      const int vo = mV*16 + r;
      const int f = 32*ks + 16*(e>>2) + 4*lg + (e&3);
      Vp[i] = (__bf16)Vm[(size_t)vo*E_ + f];
    }
  }
}

// ---------------- Stage A: zero-LDS, zero-barrier streaming GEMM ----------------
// Wave owns 32 batch rows (2 tiles) x all 256 outputs; then v-GEMM from regs.
__global__ __launch_bounds__(256) void k_stageA(
    const float* __restrict__ obs, const float* __restrict__ act,
    const float* __restrict__ zscale, const float* __restrict__ zshift,
    const __bf16* __restrict__ Ap, const __bf16* __restrict__ Vp,
    uint2* __restrict__ si_pk, uint2* __restrict__ v_pk){
  const int a = blockIdx.y, t = threadIdx.x;
  const int w = t >> 6, l = t & 63, l15 = l & 15, lg = l >> 4;
  const int bt0 = blockIdx.x*8 + w*2;
  const size_t row0 = (size_t)bt0*16 + l15;
  const size_t row1 = row0 + 16;
  const bf16x8* Afr = (const bf16x8*)Ap + (size_t)a*(KA*16*64) + l;

  f32x4 acc[16][2] = {};
  #pragma unroll 2
  for (int ks = 0; ks < KA; ++ks){
    bf16x8 zb0, zb1;
    if (ks < 10){
      const int k = ks*32 + lg*8;
      const float4 s0 = *(const float4*)(zscale + a*F_ + k);
      const float4 s1 = *(const float4*)(zscale + a*F_ + k + 4);
      const float4 h0 = *(const float4*)(zshift + a*F_ + k);
      const float4 h1 = *(const float4*)(zshift + a*F_ + k + 4);
      const float *p0, *p1;
      if (k < O_){
        p0 = obs + ((size_t)a*B_ + row0)*O_ + k;
        p1 = obs + ((size_t)a*B_ + row1)*O_ + k;
      } else {
        p0 = act + ((size_t)a*B_ + row0)*C_ + (k - O_);
        p1 = act + ((size_t)a*B_ + row1)*C_ + (k - O_);
      }
      const float4 xa0 = *(const float4*)p0, xa1 = *(const float4*)(p0 + 4);
      const float4 xb0 = *(const float4*)p1, xb1 = *(const float4*)(p1 + 4);
      zb0 = pkz(xa0, xa1, s0, s1, h0, h1);
      zb1 = pkz(xb0, xb1, s0, s1, h0, h1);
    } else {
      bf16x8 zz = {};
      if (lg == 0) zz[0] = (__bf16)1.0f;
      zb0 = zz; zb1 = zz;
    }
    const bf16x8* Ak = Afr + (size_t)ks*16*64;
    #pragma unroll
    for (int mO = 0; mO < 16; ++mO){
      const bf16x8 af = Ak[mO*64];
      acc[mO][0] = mfma16(af, zb0, acc[mO][0]);
      acc[mO][1] = mfma16(af, zb1, acc[mO][1]);
    }
  }
  #pragma unroll
  for (int mO = 0; mO < 16; ++mO){
    acc[mO][0] = lrelu4(acc[mO][0]);
    acc[mO][1] = lrelu4(acc[mO][1]);
  }
  // store si (outputs 128..255) packed C-frag, coalesced 8B/lane
  #pragma unroll
  for (int mS = 0; mS < 8; ++mS){
    si_pk[(((size_t)a*NBT + bt0    )*8 + mS)*64 + l] = pk4(acc[8+mS][0]);
    si_pk[(((size_t)a*NBT + bt0 + 1)*8 + mS)*64 + l] = pk4(acc[8+mS][1]);
  }
  // v-GEMM straight from e-registers (pi-packed B-frags are free)
  const bf16x8* Vfr = (const bf16x8*)Vp + l;
  f32x4 vacc[8][2] = {};
  #pragma unroll
  for (int ks = 0; ks < 4; ++ks){
    const bf16x8 x0 = pk8(acc[2*ks][0], acc[2*ks+1][0]);
    const bf16x8 x1 = pk8(acc[2*ks][1], acc[2*ks+1][1]);
    #pragma unroll
    for (int mV = 0; mV < 8; ++mV){
      const bf16x8 af = Vfr[(ks*8 + mV)*64];
      vacc[mV][0] = mfma16(af, x0, vacc[mV][0]);
      vacc[mV][1] = mfma16(af, x1, vacc[mV][1]);
    }
  }
  #pragma unroll
  for (int mV = 0; mV < 8; ++mV){
    v_pk[(((size_t)a*NBT + bt0    )*8 + mV)*64 + l] = pk4(lrelu4(vacc[mV][0]));
    v_pk[(((size_t)a*NBT + bt0 + 1)*8 + mV)*64 + l] = pk4(lrelu4(vacc[mV][1]));
  }
}

// ---------------- vsum over agents ----------------
__global__ void k_vsum(const uint2* __restrict__ v_pk, float4* __restrict__ vsum_pk){
  const size_t i = (size_t)blockIdx.x*256 + threadIdx.x;   // < NBT*8*64
  const size_t per_a = (size_t)NBT*8*64;
  float4 s = {0.f, 0.f, 0.f, 0.f};
  #pragma unroll
  for (int a = 0; a < A_; ++a){
    union { uint2 q; __bf16 b[4]; } c; c.q = v_pk[a*per_a + i];
    s.x += (float)c.b[0]; s.y += (float)c.b[1];
    s.z += (float)c.b[2]; s.w += (float)c.b[3];
  }
  vsum_pk[i] = s;
}

// ---------------- argmax(action) per row ----------------
__global__ void k_ids(const float* __restrict__ act, int* __restrict__ ids){
  const int t = threadIdx.x;
  const size_t row = (size_t)blockIdx.x*16 + (t >> 4);
  const int j = t & 15;
  float4 v = *((const float4*)act + row*16 + j);
  float best = v.x; int bi = j*4;
  if (v.y > best){ best = v.y; bi = j*4+1; }
  if (v.z > best){ best = v.z; bi = j*4+2; }
  if (v.w > best){ best = v.w; bi = j*4+3; }
  #pragma unroll
  for (int m = 1; m < 16; m <<= 1){
    float ob = __shfl_xor(best, m, 64);
    int oi = __shfl_xor(bi, m, 64);
    if (ob > best || (ob == best && oi < bi)){ best = ob; bi = oi; }
  }
  if (j == 0) ids[row] = bi;
}

// ---------------- Stage C: x -> h -> q -> gather (zero-barrier k-loops) ----------------
__global__ __launch_bounds__(256) void k_stageC(
    const uint2* __restrict__ si_pk, const uint2* __restrict__ v_pk,
    const float4* __restrict__ vsum_pk,
    const __bf16* __restrict__ B1p, const __bf16* __restrict__ B2p,
    const int* __restrict__ ids, float* __restrict__ out){
  __shared__ float qs[4][2][64][17];
  const int a = blockIdx.y, t = threadIdx.x;
  const int w = t >> 6, l = t & 63, l15 = l & 15, lg = l >> 4;
  const int bt0 = blockIdx.x*8 + w*2;
  const bf16x8* A1 = (const bf16x8*)B1p + (size_t)a*(K1*8*64) + l;
  const bf16x8* A2 = (const bf16x8*)B2p + (size_t)a*(K2*4*64) + l;

  f32x4 hacc[8][2] = {};
  #pragma unroll 2
  for (int ks = 0; ks < K1; ++ks){
    bf16x8 xb0, xb1;
    if (ks < 4){
      const size_t cA0 = ((size_t)(bt0    )*8 + 2*ks)*64 + l;
      const size_t cA1 = ((size_t)(bt0 + 1)*8 + 2*ks)*64 + l;
      const float4 sA0 = *(const float4*)(vsum_pk + cA0);
      const float4 sB0 = *(const float4*)(vsum_pk + cA0 + 64);
      const float4 sA1 = *(const float4*)(vsum_pk + cA1);
      const float4 sB1 = *(const float4*)(vsum_pk + cA1 + 64);
      const uint2 vA0 = v_pk[(size_t)a*NBT*8*64 + cA0];
      const uint2 vB0 = v_pk[(size_t)a*NBT*8*64 + cA0 + 64];
      const uint2 vA1 = v_pk[(size_t)a*NBT*8*64 + cA1];
      const uint2 vB1 = v_pk[(size_t)a*NBT*8*64 + cA1 + 64];
      xb0 = pk8(sub4(sA0, vA0), sub4(sB0, vB0));
      xb1 = pk8(sub4(sA1, vA1), sub4(sB1, vB1));
    } else if (ks < 8){
      const size_t cA0 = (((size_t)a*NBT + bt0    )*8 + 2*(ks-4))*64 + l;
      const size_t cA1 = (((size_t)a*NBT + bt0 + 1)*8 + 2*(ks-4))*64 + l;
      xb0 = cat2(si_pk[cA0], si_pk[cA0 + 64]);
      xb1 = cat2(si_pk[cA1], si_pk[cA1 + 64]);
    } else {
      bf16x8 zz = {};
      if (lg == 0) zz[0] = (__bf16)1.0f;
      xb0 = zz; xb1 = zz;
    }
    const bf16x8* Ak = A1 + (size_t)ks*8*64;
    #pragma unroll
    for (int mH = 0; mH < 8; ++mH){
      const bf16x8 af = Ak[mH*64];
      hacc[mH][0] = mfma16(af, xb0, hacc[mH][0]);
      hacc[mH][1] = mfma16(af, xb1, hacc[mH][1]);
    }
  }
  #pragma unroll
  for (int mH = 0; mH < 8; ++mH){
    hacc[mH][0] = lrelu4(hacc[mH][0]);
    hacc[mH][1] = lrelu4(hacc[mH][1]);
  }
  f32x4 qacc[4][2] = {};
  #pragma unroll
  for (int ks = 0; ks < K2; ++ks){
    bf16x8 hb0, hb1;
    if (ks < 4){
      hb0 = pk8(hacc[2*ks][0], hacc[2*ks+1][0]);
      hb1 = pk8(hacc[2*ks][1], hacc[2*ks+1][1]);
    } else {
      bf16x8 zz = {};
      if (lg == 0) zz[0] = (__bf16)1.0f;
      hb0 = zz; hb1 = zz;
    }
    const bf16x8* Ak = A2 + (size_t)ks*4*64;
    #pragma unroll
    for (int mC = 0; mC < 4; ++mC){
      const bf16x8 af = Ak[mC*64];
      qacc[mC][0] = mfma16(af, hb0, qacc[mC][0]);
      qacc[mC][1] = mfma16(af, hb1, qacc[mC][1]);
    }
  }
  // gather: q C-layout -> LDS -> pick argmax column
  #pragma unroll
  for (int mC = 0; mC < 4; ++mC)
    #pragma unroll
    for (int j = 0; j < 4; ++j){
      qs[w][0][16*mC + 4*lg + j][l15] = qacc[mC][0][j];
      qs[w][1][16*mC + 4*lg + j][l15] = qacc[mC][1][j];
    }
  __syncthreads();
  if (l < 32){
    const int nb = l >> 4, b15 = l & 15;
    const size_t gb = ((size_t)bt0 + nb)*16 + b15;
    const int id = ids[(size_t)a*B_ + gb];
    out[(size_t)a*B_ + gb] = qs[w][nb][id][b15];
  }
}

extern "C" void kernel_launch(void* const* d_in, const int* in_sizes, int n_in,
                              void* d_out, int out_size, void* d_ws, size_t ws_size,
                              hipStream_t stream) {
  const float* obs  = (const float*)d_in[0];
  const float* act  = (const float*)d_in[1];
  const float* ggam = (const float*)d_in[2];
  const float* gbet = (const float*)d_in[3];
  const float* gW   = (const float*)d_in[4];
  const float* gb   = (const float*)d_in[5];
  const float* sgam = (const float*)d_in[6];
  const float* sbet = (const float*)d_in[7];
  const float* sW   = (const float*)d_in[8];
  const float* sb   = (const float*)d_in[9];
  const float* f1W  = (const float*)d_in[10];
  const float* f1b  = (const float*)d_in[11];
  const float* f2W  = (const float*)d_in[12];
  const float* f2b  = (const float*)d_in[13];
  // d_in[14]=Wq, d_in[15]=Wk dead (softmax over length-1 axis == 1)
  const float* Vm   = (const float*)d_in[16];
  float* out = (float*)d_out;

  char* base = (char*)d_ws; size_t off = 0;
  auto alloc = [&](size_t bytes) -> void* {
    off = (off + 255) & ~(size_t)255; void* p = base + off; off += bytes; return p;
  };
  float* psum    = (float*)alloc((size_t)A_*NCH*F_*4);
  float* psq     = (float*)alloc((size_t)A_*NCH*F_*4);
  float* zscale  = (float*)alloc((size_t)A_*F_*4);
  float* zshift  = (float*)alloc((size_t)A_*F_*4);
  float* gbp     = (float*)alloc((size_t)A_*E_*4);
  float* sbp     = (float*)alloc((size_t)A_*E_*4);
  __bf16* Ap     = (__bf16*)alloc((size_t)A_*KA*16*64*8*2);
  __bf16* Vp     = (__bf16*)alloc((size_t)4*8*64*8*2);
  __bf16* B1p    = (__bf16*)alloc((size_t)A_*K1*8*64*8*2);
  __bf16* B2p    = (__bf16*)alloc((size_t)A_*K2*4*64*8*2);
  uint2* si_pk   = (uint2*)alloc((size_t)A_*NBT*8*64*8);
  uint2* v_pk    = (uint2*)alloc((size_t)A_*NBT*8*64*8);
  float4* vsum_p = (float4*)alloc((size_t)NBT*8*64*16);
  int*   ids     = (int*)alloc((size_t)A_*B_*4);
  (void)ws_size; (void)in_sizes; (void)n_in; (void)out_size;

  k_stats_partial<<<dim3(NCH, A_), 320, 0, stream>>>(obs, act, psum, psq);
  k_stats_final<<<A_, F_, 0, stream>>>(psum, psq, zscale, zshift);
  k_prep<<<A_, 256, 0, stream>>>(gW, gb, ggam, gbet, sW, sb, sgam, sbet,
                                 f1W, f1b, f2W, f2b, Vm, Ap, Vp, B1p, B2p, gbp, sbp);
  k_stageA<<<dim3(B_/128, A_), 256, 0, stream>>>(obs, act, zscale, zshift,
                                                 Ap, Vp, si_pk, v_pk);
  k_vsum<<<(NBT*8*64)/256, 256, 0, stream>>>(v_pk, vsum_p);
  k_ids<<<A_*B_/16, 256, 0, stream>>>(act, ids);
  k_stageC<<<dim3(B_/128, A_), 256, 0, stream>>>(si_pk, v_pk, vsum_p,
                                                 B1p, B2p, ids, out);
}

// Round 4
// 496.684 us; speedup vs baseline: 1.3708x; 1.3708x over previous
//
#include <hip/hip_runtime.h>
#include <hip/hip_bf16.h>
#include <stdint.h>

constexpr int A_ = 8, B_ = 32768, O_ = 256, C_ = 64, F_ = 320, E_ = 128;
constexpr int NCH = 128, CHROWS = B_ / NCH;
constexpr int NBT = B_ / 16;   // 2048 batch tiles of 16

typedef __attribute__((ext_vector_type(8))) __bf16 bf16x8;
typedef __attribute__((ext_vector_type(4))) float f32x4;

union U4 { uint4 u; bf16x8 v; __bf16 b[8]; };

__device__ __forceinline__ float lrelu(float x){ return x >= 0.f ? x : 0.01f * x; }
__device__ __forceinline__ f32x4 lrelu4(f32x4 x){
  f32x4 r; r[0]=lrelu(x[0]); r[1]=lrelu(x[1]); r[2]=lrelu(x[2]); r[3]=lrelu(x[3]); return r;
}
__device__ __forceinline__ f32x4 mfma16(bf16x8 a, bf16x8 b, f32x4 c){
  return __builtin_amdgcn_mfma_f32_16x16x32_bf16(a, b, c, 0, 0, 0);
}
__device__ __forceinline__ bf16x8 pk8(f32x4 lo, f32x4 hi){
  U4 r;
  r.b[0]=(__bf16)lo[0]; r.b[1]=(__bf16)lo[1]; r.b[2]=(__bf16)lo[2]; r.b[3]=(__bf16)lo[3];
  r.b[4]=(__bf16)hi[0]; r.b[5]=(__bf16)hi[1]; r.b[6]=(__bf16)hi[2]; r.b[7]=(__bf16)hi[3];
  return r.v;
}
__device__ __forceinline__ void gl_lds16(const void* g, void* s){
  __builtin_amdgcn_global_load_lds(
      (const __attribute__((address_space(1))) unsigned int*)g,
      (__attribute__((address_space(3))) unsigned int*)s, 16, 0, 0);
}

// ---------------- Stage 0: BN stats (deterministic two-stage) ----------------
__global__ void k_stats_partial(const float* __restrict__ obs,
                                const float* __restrict__ act,
                                float* __restrict__ psum, float* __restrict__ psq){
  const int f = threadIdx.x, ch = blockIdx.x, a = blockIdx.y;
  const size_t b0 = (size_t)ch * CHROWS;
  float s = 0.f, q = 0.f;
  if (f < O_){
    const float* p = obs + ((size_t)a*B_ + b0)*O_ + f;
    for (int i = 0; i < CHROWS; ++i){ float x = p[(size_t)i*O_]; s += x; q += x*x; }
  } else {
    const float* p = act + ((size_t)a*B_ + b0)*C_ + (f - O_);
    for (int i = 0; i < CHROWS; ++i){ float x = p[(size_t)i*C_]; s += x; q += x*x; }
  }
  psum[((size_t)a*NCH + ch)*F_ + f] = s;
  psq [((size_t)a*NCH + ch)*F_ + f] = q;
}

__global__ void k_stats_final(const float* __restrict__ psum, const float* __restrict__ psq,
                              float* __restrict__ zscale, float* __restrict__ zshift){
  const int f = threadIdx.x, a = blockIdx.x;
  float s = 0.f, q = 0.f;
  for (int ch = 0; ch < NCH; ++ch){
    s += psum[((size_t)a*NCH + ch)*F_ + f];
    q += psq [((size_t)a*NCH + ch)*F_ + f];
  }
  const float mean = s * (1.0f / B_);
  float var = q * (1.0f / B_) - mean * mean;
  var = fmaxf(var, 0.0f);
  const float rs = rsqrtf(var + 1e-5f);
  zscale[a*F_ + f] = rs;
  zshift[a*F_ + f] = -mean * rs;
}

// ---- pack weights as MFMA A-fragments; BN fully folded into Ap + gsb ----
// Ap  : [a][ks0..9][mO16][l][e], natural k = 32ks+8lg+e, value gW*gamma*rs (or sW...)
// B1p : [a][ks0..7][mH8][l][e], pi map f = 32ks+16(e>>2)+4lg+(e&3)
// B2p : [a][ks0..3][mC4][l][e], pi map; Vp: [ks0..3][mV8][l][e], pi map (shared)
// gsb : [a][256] folded bias (features 0..127 g-net, 128..255 s-net), linear feature order
__global__ void k_prep(const float* __restrict__ gW, const float* __restrict__ gb,
                       const float* __restrict__ ggam, const float* __restrict__ gbet,
                       const float* __restrict__ sW, const float* __restrict__ sb,
                       const float* __restrict__ sgam, const float* __restrict__ sbet,
                       const float* __restrict__ f1W, const float* __restrict__ f2W,
                       const float* __restrict__ Vm,
                       const float* __restrict__ zscale, const float* __restrict__ zshift,
                       __bf16* __restrict__ Ap, __bf16* __restrict__ Vp,
                       __bf16* __restrict__ B1p, __bf16* __restrict__ B2p,
                       float* __restrict__ gsb){
  const int a = blockIdx.x, t = threadIdx.x;
  for (int i = t; i < 10*16*64*8; i += 256){
    const int ks = i >> 13, mO = (i>>9)&15, l = (i>>3)&63, e = i&7;
    const int lg = l>>4, fo = mO*16 + (l&15), k = ks*32 + lg*8 + e;
    const float sc = zscale[a*F_ + k];
    float v;
    if (fo < 128) v = gW[(size_t)a*E_*F_ + (size_t)fo*F_ + k] * ggam[a*F_+k] * sc;
    else          v = (k < O_) ? sW[(size_t)a*E_*O_ + (size_t)(fo-128)*O_ + k] * sgam[a*O_+k] * sc : 0.f;
    Ap[(size_t)a*(10*16*64*8) + i] = (__bf16)v;
  }
  for (int i = t; i < 8*8*64*8; i += 256){
    const int ks = i >> 12, mH = (i>>9)&7, l = (i>>3)&63, e = i&7;
    const int lg = l>>4, h = mH*16 + (l&15);
    const int f = 32*ks + 16*(e>>2) + 4*lg + (e&3);
    B1p[(size_t)a*(8*8*64*8) + i] = (__bf16)f1W[(size_t)a*E_*2*E_ + (size_t)h*2*E_ + f];
  }
  for (int i = t; i < 4*4*64*8; i += 256){
    const int ks = i >> 11, mC = (i>>9)&3, l = (i>>3)&63, e = i&7;
    const int lg = l>>4, c = mC*16 + (l&15);
    const int f = 32*ks + 16*(e>>2) + 4*lg + (e&3);
    B2p[(size_t)a*(4*4*64*8) + i] = (__bf16)f2W[(size_t)a*C_*E_ + (size_t)c*E_ + f];
  }
  if (a == 0){
    for (int i = t; i < 4*8*64*8; i += 256){
      const int ks = i >> 12, mV = (i>>9)&7, l = (i>>3)&63, e = i&7;
      const int lg = l>>4, vo = mV*16 + (l&15);
      const int f = 32*ks + 16*(e>>2) + 4*lg + (e&3);
      Vp[i] = (__bf16)Vm[(size_t)vo*E_ + f];
    }
  }
  if (t < E_){
    float ag = gb[a*E_ + t], as = sb[a*E_ + t];
    for (int f = 0; f < F_; ++f){
      const float ww = gbet[a*F_+f] + ggam[a*F_+f]*zshift[a*F_+f];
      ag += ww * gW[(size_t)a*E_*F_ + (size_t)t*F_ + f];
    }
    for (int f = 0; f < O_; ++f){
      const float ww = sbet[a*O_+f] + sgam[a*O_+f]*zshift[a*F_+f];
      as += ww * sW[(size_t)a*E_*O_ + (size_t)t*O_ + f];
    }
    gsb[a*256 + t] = ag;
    gsb[a*256 + 128 + t] = as;
  }
}

// ---------------- Stage A: tri-buffered LDS pipeline, counted vmcnt ----------------
// si_q/v_q frag layout: [a][bt][j0..3][l] uint4; chunk j holds features 32j+pi
__global__ __launch_bounds__(256, 2) void k_stageA(
    const float* __restrict__ obs, const float* __restrict__ act,
    const __bf16* __restrict__ Ap, const __bf16* __restrict__ Vp,
    const float* __restrict__ gsb,
    uint4* __restrict__ si_q, uint4* __restrict__ v_q){
  __shared__ __align__(16) char smem[3*24576];   // per buf: 16KB weights + 8KB x
  const int a = blockIdx.y, t = threadIdx.x;
  const int w = t >> 6, l = t & 63, l15 = l & 15, lg = l >> 4;
  const int bt = blockIdx.x*4 + w;
  const size_t rbase = (size_t)a*B_ + (size_t)blockIdx.x*64;
  const char* ApA = (const char*)Ap + (size_t)a*163840;

  auto stage = [&](int ks, int bsel){
    char* wdst = smem + bsel*24576;
    const char* wsrc = ApA + ks*16384;
    #pragma unroll
    for (int i = 0; i < 4; ++i)
      gl_lds16(wsrc + (w*4+i)*1024 + l*16, wdst + (w*4+i)*1024);
    char* xdst = wdst + 16384;
    #pragma unroll
    for (int i = 0; i < 2; ++i){
      const int p = (w*2+i)*64 + l;
      const int row = p >> 3, jl = (p&7) ^ (row&7);   // XOR-swizzled source
      const float* xs = (ks < 8)
        ? obs + (rbase + row)*O_ + ks*32 + jl*4
        : act + (rbase + row)*C_ + (ks-8)*32 + jl*4;
      gl_lds16(xs, xdst + (w*2+i)*1024);
    }
  };

  f32x4 acc[16] = {};
  stage(0, 0);
  stage(1, 1);
  asm volatile("s_waitcnt vmcnt(6)" ::: "memory");   // step0 staged; step1 in flight
  __builtin_amdgcn_s_barrier();
  __builtin_amdgcn_sched_barrier(0);

  #pragma unroll
  for (int ks = 0; ks < 10; ++ks){
    if (ks + 2 < 10) stage(ks+2, (ks+2)%3);
    const float* xb = (const float*)(smem + (ks%3)*24576 + 16384);
    const int rl = w*16 + l15, sw = rl & 7;
    const f32x4 xlo = *(const f32x4*)(xb + (rl*8 + ((2*lg) ^ sw))*4);
    const f32x4 xhi = *(const f32x4*)(xb + (rl*8 + ((2*lg+1) ^ sw))*4);
    bf16x8 zb;
    #pragma unroll
    for (int e = 0; e < 4; ++e){ zb[e] = (__bf16)xlo[e]; zb[4+e] = (__bf16)xhi[e]; }
    const bf16x8* wc = (const bf16x8*)(smem + (ks%3)*24576);
    #pragma unroll
    for (int m = 0; m < 16; ++m)
      acc[m] = mfma16(wc[m*64 + l], zb, acc[m]);
    __builtin_amdgcn_sched_barrier(0);
    if (ks <= 7)      { asm volatile("s_waitcnt vmcnt(6)" ::: "memory"); }
    else if (ks == 8) { asm volatile("s_waitcnt vmcnt(0)" ::: "memory"); }
    if (ks < 9){
      __builtin_amdgcn_s_barrier();
      __builtin_amdgcn_sched_barrier(0);
    }
  }

  // epilogue: bias + lrelu (features mO*16+lg*4+j, linear order in gsb)
  const float* bE = gsb + a*256 + lg*4;
  #pragma unroll
  for (int m = 0; m < 16; ++m){
    const float4 b = *(const float4*)(bE + m*16);
    acc[m][0]=lrelu(acc[m][0]+b.x); acc[m][1]=lrelu(acc[m][1]+b.y);
    acc[m][2]=lrelu(acc[m][2]+b.z); acc[m][3]=lrelu(acc[m][3]+b.w);
  }
  uint4* sq = si_q + ((size_t)a*NBT + bt)*256 + l;
  #pragma unroll
  for (int j = 0; j < 4; ++j){
    U4 u; u.v = pk8(acc[8+2*j], acc[9+2*j]);
    sq[j*64] = u.u;
  }
  // v-GEMM from e-registers
  const bf16x8* Vfr = (const bf16x8*)Vp + l;
  f32x4 vacc[8] = {};
  #pragma unroll
  for (int kv = 0; kv < 4; ++kv){
    const bf16x8 xbv = pk8(acc[2*kv], acc[2*kv+1]);
    #pragma unroll
    for (int mV = 0; mV < 8; ++mV)
      vacc[mV] = mfma16(Vfr[(kv*8+mV)*64], xbv, vacc[mV]);
  }
  uint4* vq = v_q + ((size_t)a*NBT + bt)*256 + l;
  #pragma unroll
  for (int j = 0; j < 4; ++j){
    U4 u; u.v = pk8(lrelu4(vacc[2*j]), lrelu4(vacc[2*j+1]));
    vq[j*64] = u.u;
  }
}

// ---------------- vsum & x-pack: xq[a] = (sum_a' v) - v[a], frag layout ----------------
__global__ void k_vsum_x(const uint4* __restrict__ v_q, uint4* __restrict__ xq){
  const size_t i = (size_t)blockIdx.x*256 + threadIdx.x;
  const size_t per_a = (size_t)NBT*256;
  U4 va[8]; float s[8] = {0,0,0,0,0,0,0,0};
  #pragma unroll
  for (int a = 0; a < 8; ++a){
    va[a].u = v_q[a*per_a + i];
    #pragma unroll
    for (int e = 0; e < 8; ++e) s[e] += (float)va[a].b[e];
  }
  #pragma unroll
  for (int a = 0; a < 8; ++a){
    U4 o;
    #pragma unroll
    for (int e = 0; e < 8; ++e) o.b[e] = (__bf16)(s[e] - (float)va[a].b[e]);
    xq[a*per_a + i] = o.u;
  }
}

// ---------------- argmax(action) per row ----------------
__global__ void k_ids(const float* __restrict__ act, int* __restrict__ ids){
  const int t = threadIdx.x;
  const size_t row = (size_t)blockIdx.x*16 + (t >> 4);
  const int j = t & 15;
  float4 v = *((const float4*)act + row*16 + j);
  float best = v.x; int bi = j*4;
  if (v.y > best){ best = v.y; bi = j*4+1; }
  if (v.z > best){ best = v.z; bi = j*4+2; }
  if (v.w > best){ best = v.w; bi = j*4+3; }
  #pragma unroll
  for (int m = 1; m < 16; m <<= 1){
    float ob = __shfl_xor(best, m, 64);
    int oi = __shfl_xor(bi, m, 64);
    if (ob > best || (ob == best && oi < bi)){ best = ob; bi = oi; }
  }
  if (j == 0) ids[row] = bi;
}

// ---------------- Stage C: [x|si] -> h -> q -> gather ----------------
__global__ __launch_bounds__(256, 4) void k_stageC(
    const uint4* __restrict__ xq, const uint4* __restrict__ si_q,
    const __bf16* __restrict__ B1p, const __bf16* __restrict__ B2p,
    const float* __restrict__ f1b, const float* __restrict__ f2b,
    const int* __restrict__ ids, float* __restrict__ out){
  __shared__ __align__(16) char wsm[2*8192];
  __shared__ float qs[4][64][17];
  const int a = blockIdx.y, t = threadIdx.x;
  const int w = t >> 6, l = t & 63, l15 = l & 15, lg = l >> 4;
  const int bt = blockIdx.x*4 + w;
  const char* B1A = (const char*)B1p + (size_t)a*65536;
  const uint4* xpA = xq   + ((size_t)a*NBT + bt)*256 + l;
  const uint4* xpB = si_q + ((size_t)a*NBT + bt)*256 + l;

  auto stage1 = [&](int ks, int bsel){
    const char* src = B1A + ks*8192;
    char* dst = wsm + bsel*8192;
    #pragma unroll
    for (int i = 0; i < 2; ++i)
      gl_lds16(src + (w*2+i)*1024 + l*16, dst + (w*2+i)*1024);
  };

  f32x4 hacc[8] = {};
  stage1(0, 0);
  uint4 xr0 = xpA[0];
  uint4 xr1 = xpA[64];
  asm volatile("s_waitcnt vmcnt(2)" ::: "memory");
  __builtin_amdgcn_s_barrier();
  __builtin_amdgcn_sched_barrier(0);

  #pragma unroll
  for (int ks = 0; ks < 8; ++ks){
    U4 zc; zc.u = (ks & 1) ? xr1 : xr0;
    const bf16x8 zb = zc.v;
    if (ks + 1 < 8) stage1(ks+1, (ks+1)&1);
    if (ks + 2 < 8){
      const uint4 nx = (ks+2 < 4) ? xpA[(ks+2)*64] : xpB[(ks-2)*64];
      if (ks & 1) xr1 = nx; else xr0 = nx;
    }
    const bf16x8* wc = (const bf16x8*)(wsm + (ks&1)*8192);
    #pragma unroll
    for (int m = 0; m < 8; ++m)
      hacc[m] = mfma16(wc[m*64 + l], zb, hacc[m]);
    __builtin_amdgcn_sched_barrier(0);
    if (ks <= 5)      { asm volatile("s_waitcnt vmcnt(1)" ::: "memory"); }
    else if (ks == 6) { asm volatile("s_waitcnt vmcnt(0)" ::: "memory"); }
    if (ks < 7){
      __builtin_amdgcn_s_barrier();
      __builtin_amdgcn_sched_barrier(0);
    }
  }

  const float* bH = f1b + a*E_ + lg*4;
  #pragma unroll
  for (int m = 0; m < 8; ++m){
    const float4 b = *(const float4*)(bH + m*16);
    hacc[m][0]=lrelu(hacc[m][0]+b.x); hacc[m][1]=lrelu(hacc[m][1]+b.y);
    hacc[m][2]=lrelu(hacc[m][2]+b.z); hacc[m][3]=lrelu(hacc[m][3]+b.w);
  }
  const bf16x8* A2 = (const bf16x8*)B2p + (size_t)a*(4*4*64) + l;
  f32x4 qacc[4] = {};
  #pragma unroll
  for (int kq = 0; kq < 4; ++kq){
    const bf16x8 hb = pk8(hacc[2*kq], hacc[2*kq+1]);
    #pragma unroll
    for (int mC = 0; mC < 4; ++mC)
      qacc[mC] = mfma16(A2[(kq*4+mC)*64], hb, qacc[mC]);
  }
  const float* bQ = f2b + a*C_ + lg*4;
  #pragma unroll
  for (int mC = 0; mC < 4; ++mC){
    const float4 b = *(const float4*)(bQ + mC*16);
    qs[w][16*mC + 4*lg + 0][l15] = qacc[mC][0] + b.x;
    qs[w][16*mC + 4*lg + 1][l15] = qacc[mC][1] + b.y;
    qs[w][16*mC + 4*lg + 2][l15] = qacc[mC][2] + b.z;
    qs[w][16*mC + 4*lg + 3][l15] = qacc[mC][3] + b.w;
  }
  if (l < 16){
    const size_t gb = (size_t)bt*16 + l;
    const int id = ids[(size_t)a*B_ + gb];
    out[(size_t)a*B_ + gb] = qs[w][id][l];
  }
}

extern "C" void kernel_launch(void* const* d_in, const int* in_sizes, int n_in,
                              void* d_out, int out_size, void* d_ws, size_t ws_size,
                              hipStream_t stream) {
  const float* obs  = (const float*)d_in[0];
  const float* act  = (const float*)d_in[1];
  const float* ggam = (const float*)d_in[2];
  const float* gbet = (const float*)d_in[3];
  const float* gW   = (const float*)d_in[4];
  const float* gb   = (const float*)d_in[5];
  const float* sgam = (const float*)d_in[6];
  const float* sbet = (const float*)d_in[7];
  const float* sW   = (const float*)d_in[8];
  const float* sb   = (const float*)d_in[9];
  const float* f1W  = (const float*)d_in[10];
  const float* f1b  = (const float*)d_in[11];
  const float* f2W  = (const float*)d_in[12];
  const float* f2b  = (const float*)d_in[13];
  // d_in[14]=Wq, d_in[15]=Wk dead (softmax over length-1 axis == 1)
  const float* Vm   = (const float*)d_in[16];
  float* out = (float*)d_out;

  char* base = (char*)d_ws; size_t off = 0;
  auto alloc = [&](size_t bytes) -> void* {
    off = (off + 255) & ~(size_t)255; void* p = base + off; off += bytes; return p;
  };
  float* psum   = (float*)alloc((size_t)A_*NCH*F_*4);
  float* psq    = (float*)alloc((size_t)A_*NCH*F_*4);
  float* zscale = (float*)alloc((size_t)A_*F_*4);
  float* zshift = (float*)alloc((size_t)A_*F_*4);
  float* gsb    = (float*)alloc((size_t)A_*256*4);
  __bf16* Ap    = (__bf16*)alloc((size_t)A_*10*16*64*8*2);
  __bf16* Vp    = (__bf16*)alloc((size_t)4*8*64*8*2);
  __bf16* B1p   = (__bf16*)alloc((size_t)A_*8*8*64*8*2);
  __bf16* B2p   = (__bf16*)alloc((size_t)A_*4*4*64*8*2);
  uint4* si_q   = (uint4*)alloc((size_t)A_*NBT*256*16);
  uint4* v_q    = (uint4*)alloc((size_t)A_*NBT*256*16);
  uint4* xq     = (uint4*)alloc((size_t)A_*NBT*256*16);
  int*   ids    = (int*)alloc((size_t)A_*B_*4);
  (void)ws_size; (void)in_sizes; (void)n_in; (void)out_size;

  k_stats_partial<<<dim3(NCH, A_), 320, 0, stream>>>(obs, act, psum, psq);
  k_stats_final<<<A_, F_, 0, stream>>>(psum, psq, zscale, zshift);
  k_prep<<<A_, 256, 0, stream>>>(gW, gb, ggam, gbet, sW, sb, sgam, sbet,
                                 f1W, f2W, Vm, zscale, zshift,
                                 Ap, Vp, B1p, B2p, gsb);
  k_stageA<<<dim3(NBT/4, A_), 256, 0, stream>>>(obs, act, Ap, Vp, gsb, si_q, v_q);
  k_vsum_x<<<(NBT*256)/256, 256, 0, stream>>>(v_q, xq);
  k_ids<<<A_*B_/16, 256, 0, stream>>>(act, ids);
  k_stageC<<<dim3(NBT/4, A_), 256, 0, stream>>>(xq, si_q, B1p, B2p, f1b, f2b, ids, out);
}

// Round 5
// 314.724 us; speedup vs baseline: 2.1634x; 1.5782x over previous
//
#include <hip/hip_runtime.h>
#include <hip/hip_bf16.h>
#include <stdint.h>

constexpr int A_ = 8, B_ = 32768, O_ = 256, C_ = 64, F_ = 320, E_ = 128;
constexpr int NCH = 128, CHROWS = B_ / NCH;
constexpr int NBT = B_ / 16;   // 2048 batch tiles of 16

typedef __attribute__((ext_vector_type(8))) __bf16 bf16x8;
typedef __attribute__((ext_vector_type(4))) float f32x4;

union U4 { uint4 u; bf16x8 v; __bf16 b[8]; };

__device__ __forceinline__ float lrelu(float x){ return x >= 0.f ? x : 0.01f * x; }
__device__ __forceinline__ f32x4 lrelu4(f32x4 x){
  f32x4 r; r[0]=lrelu(x[0]); r[1]=lrelu(x[1]); r[2]=lrelu(x[2]); r[3]=lrelu(x[3]); return r;
}
__device__ __forceinline__ f32x4 mfma16(bf16x8 a, bf16x8 b, f32x4 c){
  return __builtin_amdgcn_mfma_f32_16x16x32_bf16(a, b, c, 0, 0, 0);
}
__device__ __forceinline__ bf16x8 pk8(f32x4 lo, f32x4 hi){
  U4 r;
  r.b[0]=(__bf16)lo[0]; r.b[1]=(__bf16)lo[1]; r.b[2]=(__bf16)lo[2]; r.b[3]=(__bf16)lo[3];
  r.b[4]=(__bf16)hi[0]; r.b[5]=(__bf16)hi[1]; r.b[6]=(__bf16)hi[2]; r.b[7]=(__bf16)hi[3];
  return r.v;
}
__device__ __forceinline__ void gl_lds16(const void* g, void* s){
  __builtin_amdgcn_global_load_lds(
      (const __attribute__((address_space(1))) unsigned int*)g,
      (__attribute__((address_space(3))) unsigned int*)s, 16, 0, 0);
}

// ---------------- Stage 0: BN stats (deterministic two-stage) ----------------
__global__ void k_stats_partial(const float* __restrict__ obs,
                                const float* __restrict__ act,
                                float* __restrict__ psum, float* __restrict__ psq){
  const int f = threadIdx.x, ch = blockIdx.x, a = blockIdx.y;
  const size_t b0 = (size_t)ch * CHROWS;
  float s = 0.f, q = 0.f;
  if (f < O_){
    const float* p = obs + ((size_t)a*B_ + b0)*O_ + f;
    for (int i = 0; i < CHROWS; ++i){ float x = p[(size_t)i*O_]; s += x; q += x*x; }
  } else {
    const float* p = act + ((size_t)a*B_ + b0)*C_ + (f - O_);
    for (int i = 0; i < CHROWS; ++i){ float x = p[(size_t)i*C_]; s += x; q += x*x; }
  }
  psum[((size_t)a*NCH + ch)*F_ + f] = s;
  psq [((size_t)a*NCH + ch)*F_ + f] = q;
}

__global__ void k_stats_final(const float* __restrict__ psum, const float* __restrict__ psq,
                              float* __restrict__ zscale, float* __restrict__ zshift){
  const int f = threadIdx.x, a = blockIdx.x;
  float s = 0.f, q = 0.f;
  for (int ch = 0; ch < NCH; ++ch){
    s += psum[((size_t)a*NCH + ch)*F_ + f];
    q += psq [((size_t)a*NCH + ch)*F_ + f];
  }
  const float mean = s * (1.0f / B_);
  float var = q * (1.0f / B_) - mean * mean;
  var = fmaxf(var, 0.0f);
  const float rs = rsqrtf(var + 1e-5f);
  zscale[a*F_ + f] = rs;
  zshift[a*F_ + f] = -mean * rs;
}

// ---- pack weights as MFMA A-fragments; BN fully folded into Ap + gsb ----
// Ap  : [a][ks0..9][mO16][l][e], natural k = 32ks+8lg+e, value gW*gamma*rs (or sW...)
// B1p : [a][ks0..7][mH8][l][e], pi map f = 32ks+16(e>>2)+4lg+(e&3)
// B2p : [a][ks0..3][mC4][l][e], pi map; Vp: [ks0..3][mV8][l][e], pi map (shared)
// Grid dim3(32, A_): 256 blocks, grid-stride loops (round-4 k_prep was 8 blocks -> 206us).
__global__ void k_prep_pack(const float* __restrict__ gW, const float* __restrict__ ggam,
                            const float* __restrict__ sW, const float* __restrict__ sgam,
                            const float* __restrict__ f1W, const float* __restrict__ f2W,
                            const float* __restrict__ Vm, const float* __restrict__ zscale,
                            __bf16* __restrict__ Ap, __bf16* __restrict__ Vp,
                            __bf16* __restrict__ B1p, __bf16* __restrict__ B2p){
  const int a = blockIdx.y;
  const int t0 = blockIdx.x*256 + threadIdx.x;   // 0..8191
  constexpr int STR = 32*256;
  for (int i = t0; i < 10*16*64*8; i += STR){
    const int ks = i >> 13, mO = (i>>9)&15, l = (i>>3)&63, e = i&7;
    const int lg = l>>4, fo = mO*16 + (l&15), k = ks*32 + lg*8 + e;
    const float sc = zscale[a*F_ + k];
    float v;
    if (fo < 128) v = gW[(size_t)a*E_*F_ + (size_t)fo*F_ + k] * ggam[a*F_+k] * sc;
    else          v = (k < O_) ? sW[(size_t)a*E_*O_ + (size_t)(fo-128)*O_ + k] * sgam[a*O_+k] * sc : 0.f;
    Ap[(size_t)a*(10*16*64*8) + i] = (__bf16)v;
  }
  for (int i = t0; i < 8*8*64*8; i += STR){
    const int ks = i >> 12, mH = (i>>9)&7, l = (i>>3)&63, e = i&7;
    const int lg = l>>4, h = mH*16 + (l&15);
    const int f = 32*ks + 16*(e>>2) + 4*lg + (e&3);
    B1p[(size_t)a*(8*8*64*8) + i] = (__bf16)f1W[(size_t)a*E_*2*E_ + (size_t)h*2*E_ + f];
  }
  for (int i = t0; i < 4*4*64*8; i += STR){
    const int ks = i >> 11, mC = (i>>9)&3, l = (i>>3)&63, e = i&7;
    const int lg = l>>4, c = mC*16 + (l&15);
    const int f = 32*ks + 16*(e>>2) + 4*lg + (e&3);
    B2p[(size_t)a*(4*4*64*8) + i] = (__bf16)f2W[(size_t)a*C_*E_ + (size_t)c*E_ + f];
  }
  if (a == 0){
    for (int i = t0; i < 4*8*64*8; i += STR){
      const int ks = i >> 12, mV = (i>>9)&7, l = (i>>3)&63, e = i&7;
      const int lg = l>>4, vo = mV*16 + (l&15);
      const int f = 32*ks + 16*(e>>2) + 4*lg + (e&3);
      Vp[i] = (__bf16)Vm[(size_t)vo*E_ + f];
    }
  }
}

// folded biases: gsb[a][0..127] = gb + (gbet + ggam*zshift) @ gW^T ; [128..255] s-net
__global__ void k_prep_bias(const float* __restrict__ gW, const float* __restrict__ gb,
                            const float* __restrict__ ggam, const float* __restrict__ gbet,
                            const float* __restrict__ sW, const float* __restrict__ sb,
                            const float* __restrict__ sgam, const float* __restrict__ sbet,
                            const float* __restrict__ zshift, float* __restrict__ gsb){
  __shared__ float ww[F_];
  __shared__ float part[2][128];
  const int a = blockIdx.y, t = threadIdx.x;
  const int o = t & 127, h = t >> 7;
  if (blockIdx.x == 0){
    for (int f = t; f < F_; f += 256)
      ww[f] = gbet[a*F_+f] + ggam[a*F_+f]*zshift[a*F_+f];
    __syncthreads();
    float s = 0.f;
    #pragma unroll 4
    for (int f = h*160; f < h*160 + 160; f += 4){
      const float4 wv = *(const float4*)&gW[(size_t)a*E_*F_ + (size_t)o*F_ + f];
      s += wv.x*ww[f] + wv.y*ww[f+1] + wv.z*ww[f+2] + wv.w*ww[f+3];
    }
    part[h][o] = s;
    __syncthreads();
    if (t < 128) gsb[a*256 + t] = gb[a*E_+t] + part[0][t] + part[1][t];
  } else {
    for (int f = t; f < O_; f += 256)
      ww[f] = sbet[a*O_+f] + sgam[a*O_+f]*zshift[a*F_+f];
    __syncthreads();
    float s = 0.f;
    #pragma unroll 4
    for (int f = h*128; f < h*128 + 128; f += 4){
      const float4 wv = *(const float4*)&sW[(size_t)a*E_*O_ + (size_t)o*O_ + f];
      s += wv.x*ww[f] + wv.y*ww[f+1] + wv.z*ww[f+2] + wv.w*ww[f+3];
    }
    part[h][o] = s;
    __syncthreads();
    if (t < 128) gsb[a*256 + 128 + t] = sb[a*E_+t] + part[0][t] + part[1][t];
  }
}

// ---------------- Stage A: tri-buffered LDS pipeline, counted vmcnt ----------------
// si_q/v_q frag layout: [a][bt][j0..3][l] uint4; chunk j holds features 32j+pi
__global__ __launch_bounds__(256, 2) void k_stageA(
    const float* __restrict__ obs, const float* __restrict__ act,
    const __bf16* __restrict__ Ap, const __bf16* __restrict__ Vp,
    const float* __restrict__ gsb,
    uint4* __restrict__ si_q, uint4* __restrict__ v_q){
  __shared__ __align__(16) char smem[3*24576];   // per buf: 16KB weights + 8KB x
  const int a = blockIdx.y, t = threadIdx.x;
  const int w = t >> 6, l = t & 63, l15 = l & 15, lg = l >> 4;
  const int bt = blockIdx.x*4 + w;
  const size_t rbase = (size_t)a*B_ + (size_t)blockIdx.x*64;
  const char* ApA = (const char*)Ap + (size_t)a*163840;

  auto stage = [&](int ks, int bsel){
    char* wdst = smem + bsel*24576;
    const char* wsrc = ApA + ks*16384;
    #pragma unroll
    for (int i = 0; i < 4; ++i)
      gl_lds16(wsrc + (w*4+i)*1024 + l*16, wdst + (w*4+i)*1024);
    char* xdst = wdst + 16384;
    #pragma unroll
    for (int i = 0; i < 2; ++i){
      const int p = (w*2+i)*64 + l;
      const int row = p >> 3, jl = (p&7) ^ (row&7);   // XOR-swizzled source
      const float* xs = (ks < 8)
        ? obs + (rbase + row)*O_ + ks*32 + jl*4
        : act + (rbase + row)*C_ + (ks-8)*32 + jl*4;
      gl_lds16(xs, xdst + (w*2+i)*1024);
    }
  };

  f32x4 acc[16] = {};
  stage(0, 0);
  stage(1, 1);
  asm volatile("s_waitcnt vmcnt(6)" ::: "memory");   // step0 staged; step1 in flight
  __builtin_amdgcn_s_barrier();
  __builtin_amdgcn_sched_barrier(0);

  #pragma unroll
  for (int ks = 0; ks < 10; ++ks){
    if (ks + 2 < 10) stage(ks+2, (ks+2)%3);
    const float* xb = (const float*)(smem + (ks%3)*24576 + 16384);
    const int rl = w*16 + l15, sw = rl & 7;
    const f32x4 xlo = *(const f32x4*)(xb + (rl*8 + ((2*lg) ^ sw))*4);
    const f32x4 xhi = *(const f32x4*)(xb + (rl*8 + ((2*lg+1) ^ sw))*4);
    bf16x8 zb;
    #pragma unroll
    for (int e = 0; e < 4; ++e){ zb[e] = (__bf16)xlo[e]; zb[4+e] = (__bf16)xhi[e]; }
    const bf16x8* wc = (const bf16x8*)(smem + (ks%3)*24576);
    #pragma unroll
    for (int m = 0; m < 16; ++m)
      acc[m] = mfma16(wc[m*64 + l], zb, acc[m]);
    __builtin_amdgcn_sched_barrier(0);
    if (ks <= 7)      { asm volatile("s_waitcnt vmcnt(6)" ::: "memory"); }
    else if (ks == 8) { asm volatile("s_waitcnt vmcnt(0)" ::: "memory"); }
    if (ks < 9){
      __builtin_amdgcn_s_barrier();
      __builtin_amdgcn_sched_barrier(0);
    }
  }

  // epilogue: bias + lrelu (features mO*16+lg*4+j, linear order in gsb)
  const float* bE = gsb + a*256 + lg*4;
  #pragma unroll
  for (int m = 0; m < 16; ++m){
    const float4 b = *(const float4*)(bE + m*16);
    acc[m][0]=lrelu(acc[m][0]+b.x); acc[m][1]=lrelu(acc[m][1]+b.y);
    acc[m][2]=lrelu(acc[m][2]+b.z); acc[m][3]=lrelu(acc[m][3]+b.w);
  }
  uint4* sq = si_q + ((size_t)a*NBT + bt)*256 + l;
  #pragma unroll
  for (int j = 0; j < 4; ++j){
    U4 u; u.v = pk8(acc[8+2*j], acc[9+2*j]);
    sq[j*64] = u.u;
  }
  // v-GEMM from e-registers
  const bf16x8* Vfr = (const bf16x8*)Vp + l;
  f32x4 vacc[8] = {};
  #pragma unroll
  for (int kv = 0; kv < 4; ++kv){
    const bf16x8 xbv = pk8(acc[2*kv], acc[2*kv+1]);
    #pragma unroll
    for (int mV = 0; mV < 8; ++mV)
      vacc[mV] = mfma16(Vfr[(kv*8+mV)*64], xbv, vacc[mV]);
  }
  uint4* vq = v_q + ((size_t)a*NBT + bt)*256 + l;
  #pragma unroll
  for (int j = 0; j < 4; ++j){
    U4 u; u.v = pk8(lrelu4(vacc[2*j]), lrelu4(vacc[2*j+1]));
    vq[j*64] = u.u;
  }
}

// ---------------- vsum & x-pack: xq[a] = (sum_a' v) - v[a], frag layout ----------------
__global__ void k_vsum_x(const uint4* __restrict__ v_q, uint4* __restrict__ xq){
  const size_t i = (size_t)blockIdx.x*256 + threadIdx.x;
  const size_t per_a = (size_t)NBT*256;
  U4 va[8]; float s[8] = {0,0,0,0,0,0,0,0};
  #pragma unroll
  for (int a = 0; a < 8; ++a){
    va[a].u = v_q[a*per_a + i];
    #pragma unroll
    for (int e = 0; e < 8; ++e) s[e] += (float)va[a].b[e];
  }
  #pragma unroll
  for (int a = 0; a < 8; ++a){
    U4 o;
    #pragma unroll
    for (int e = 0; e < 8; ++e) o.b[e] = (__bf16)(s[e] - (float)va[a].b[e]);
    xq[a*per_a + i] = o.u;
  }
}

// ---------------- argmax(action) per row ----------------
__global__ void k_ids(const float* __restrict__ act, int* __restrict__ ids){
  const int t = threadIdx.x;
  const size_t row = (size_t)blockIdx.x*16 + (t >> 4);
  const int j = t & 15;
  float4 v = *((const float4*)act + row*16 + j);
  float best = v.x; int bi = j*4;
  if (v.y > best){ best = v.y; bi = j*4+1; }
  if (v.z > best){ best = v.z; bi = j*4+2; }
  if (v.w > best){ best = v.w; bi = j*4+3; }
  #pragma unroll
  for (int m = 1; m < 16; m <<= 1){
    float ob = __shfl_xor(best, m, 64);
    int oi = __shfl_xor(bi, m, 64);
    if (ob > best || (ob == best && oi < bi)){ best = ob; bi = oi; }
  }
  if (j == 0) ids[row] = bi;
}

// ---------------- Stage C: [x|si] -> h -> q -> gather ----------------
__global__ __launch_bounds__(256, 4) void k_stageC(
    const uint4* __restrict__ xq, const uint4* __restrict__ si_q,
    const __bf16* __restrict__ B1p, const __bf16* __restrict__ B2p,
    const float* __restrict__ f1b, const float* __restrict__ f2b,
    const int* __restrict__ ids, float* __restrict__ out){
  __shared__ __align__(16) char wsm[2*8192];
  __shared__ float qs[4][64][17];
  const int a = blockIdx.y, t = threadIdx.x;
  const int w = t >> 6, l = t & 63, l15 = l & 15, lg = l >> 4;
  const int bt = blockIdx.x*4 + w;
  const char* B1A = (const char*)B1p + (size_t)a*65536;
  const uint4* xpA = xq   + ((size_t)a*NBT + bt)*256 + l;
  const uint4* xpB = si_q + ((size_t)a*NBT + bt)*256 + l;

  auto stage1 = [&](int ks, int bsel){
    const char* src = B1A + ks*8192;
    char* dst = wsm + bsel*8192;
    #pragma unroll
    for (int i = 0; i < 2; ++i)
      gl_lds16(src + (w*2+i)*1024 + l*16, dst + (w*2+i)*1024);
  };

  f32x4 hacc[8] = {};
  stage1(0, 0);
  uint4 xr0 = xpA[0];
  uint4 xr1 = xpA[64];
  asm volatile("s_waitcnt vmcnt(2)" ::: "memory");
  __builtin_amdgcn_s_barrier();
  __builtin_amdgcn_sched_barrier(0);

  #pragma unroll
  for (int ks = 0; ks < 8; ++ks){
    U4 zc; zc.u = (ks & 1) ? xr1 : xr0;
    const bf16x8 zb = zc.v;
    if (ks + 1 < 8) stage1(ks+1, (ks+1)&1);
    if (ks + 2 < 8){
      const uint4 nx = (ks+2 < 4) ? xpA[(ks+2)*64] : xpB[(ks-2)*64];
      if (ks & 1) xr1 = nx; else xr0 = nx;
    }
    const bf16x8* wc = (const bf16x8*)(wsm + (ks&1)*8192);
    #pragma unroll
    for (int m = 0; m < 8; ++m)
      hacc[m] = mfma16(wc[m*64 + l], zb, hacc[m]);
    __builtin_amdgcn_sched_barrier(0);
    if (ks <= 5)      { asm volatile("s_waitcnt vmcnt(1)" ::: "memory"); }
    else if (ks == 6) { asm volatile("s_waitcnt vmcnt(0)" ::: "memory"); }
    if (ks < 7){
      __builtin_amdgcn_s_barrier();
      __builtin_amdgcn_sched_barrier(0);
    }
  }

  const float* bH = f1b + a*E_ + lg*4;
  #pragma unroll
  for (int m = 0; m < 8; ++m){
    const float4 b = *(const float4*)(bH + m*16);
    hacc[m][0]=lrelu(hacc[m][0]+b.x); hacc[m][1]=lrelu(hacc[m][1]+b.y);
    hacc[m][2]=lrelu(hacc[m][2]+b.z); hacc[m][3]=lrelu(hacc[m][3]+b.w);
  }
  const bf16x8* A2 = (const bf16x8*)B2p + (size_t)a*(4*4*64) + l;
  f32x4 qacc[4] = {};
  #pragma unroll
  for (int kq = 0; kq < 4; ++kq){
    const bf16x8 hb = pk8(hacc[2*kq], hacc[2*kq+1]);
    #pragma unroll
    for (int mC = 0; mC < 4; ++mC)
      qacc[mC] = mfma16(A2[(kq*4+mC)*64], hb, qacc[mC]);
  }
  const float* bQ = f2b + a*C_ + lg*4;
  #pragma unroll
  for (int mC = 0; mC < 4; ++mC){
    const float4 b = *(const float4*)(bQ + mC*16);
    qs[w][16*mC + 4*lg + 0][l15] = qacc[mC][0] + b.x;
    qs[w][16*mC + 4*lg + 1][l15] = qacc[mC][1] + b.y;
    qs[w][16*mC + 4*lg + 2][l15] = qacc[mC][2] + b.z;
    qs[w][16*mC + 4*lg + 3][l15] = qacc[mC][3] + b.w;
  }
  if (l < 16){
    const size_t gb = (size_t)bt*16 + l;
    const int id = ids[(size_t)a*B_ + gb];
    out[(size_t)a*B_ + gb] = qs[w][id][l];
  }
}

extern "C" void kernel_launch(void* const* d_in, const int* in_sizes, int n_in,
                              void* d_out, int out_size, void* d_ws, size_t ws_size,
                              hipStream_t stream) {
  const float* obs  = (const float*)d_in[0];
  const float* act  = (const float*)d_in[1];
  const float* ggam = (const float*)d_in[2];
  const float* gbet = (const float*)d_in[3];
  const float* gW   = (const float*)d_in[4];
  const float* gb   = (const float*)d_in[5];
  const float* sgam = (const float*)d_in[6];
  const float* sbet = (const float*)d_in[7];
  const float* sW   = (const float*)d_in[8];
  const float* sb   = (const float*)d_in[9];
  const float* f1W  = (const float*)d_in[10];
  const float* f1b  = (const float*)d_in[11];
  const float* f2W  = (const float*)d_in[12];
  const float* f2b  = (const float*)d_in[13];
  // d_in[14]=Wq, d_in[15]=Wk dead (softmax over length-1 axis == 1)
  const float* Vm   = (const float*)d_in[16];
  float* out = (float*)d_out;

  char* base = (char*)d_ws; size_t off = 0;
  auto alloc = [&](size_t bytes) -> void* {
    off = (off + 255) & ~(size_t)255; void* p = base + off; off += bytes; return p;
  };
  float* psum   = (float*)alloc((size_t)A_*NCH*F_*4);
  float* psq    = (float*)alloc((size_t)A_*NCH*F_*4);
  float* zscale = (float*)alloc((size_t)A_*F_*4);
  float* zshift = (float*)alloc((size_t)A_*F_*4);
  float* gsb    = (float*)alloc((size_t)A_*256*4);
  __bf16* Ap    = (__bf16*)alloc((size_t)A_*10*16*64*8*2);
  __bf16* Vp    = (__bf16*)alloc((size_t)4*8*64*8*2);
  __bf16* B1p   = (__bf16*)alloc((size_t)A_*8*8*64*8*2);
  __bf16* B2p   = (__bf16*)alloc((size_t)A_*4*4*64*8*2);
  uint4* si_q   = (uint4*)alloc((size_t)A_*NBT*256*16);
  uint4* v_q    = (uint4*)alloc((size_t)A_*NBT*256*16);
  uint4* xq     = (uint4*)alloc((size_t)A_*NBT*256*16);
  int*   ids    = (int*)alloc((size_t)A_*B_*4);
  (void)ws_size; (void)in_sizes; (void)n_in; (void)out_size;

  k_stats_partial<<<dim3(NCH, A_), 320, 0, stream>>>(obs, act, psum, psq);
  k_stats_final<<<A_, F_, 0, stream>>>(psum, psq, zscale, zshift);
  k_prep_pack<<<dim3(32, A_), 256, 0, stream>>>(gW, ggam, sW, sgam, f1W, f2W, Vm,
                                                zscale, Ap, Vp, B1p, B2p);
  k_prep_bias<<<dim3(2, A_), 256, 0, stream>>>(gW, gb, ggam, gbet, sW, sb, sgam, sbet,
                                               zshift, gsb);
  k_stageA<<<dim3(NBT/4, A_), 256, 0, stream>>>(obs, act, Ap, Vp, gsb, si_q, v_q);
  k_vsum_x<<<(NBT*256)/256, 256, 0, stream>>>(v_q, xq);
  k_ids<<<A_*B_/16, 256, 0, stream>>>(act, ids);
  k_stageC<<<dim3(NBT/4, A_), 256, 0, stream>>>(xq, si_q, B1p, B2p, f1b, f2b, ids, out);
}

// Round 6
// 271.092 us; speedup vs baseline: 2.5116x; 1.1610x over previous
//
#include <hip/hip_runtime.h>
#include <hip/hip_bf16.h>
#include <stdint.h>

constexpr int A_ = 8, B_ = 32768, O_ = 256, C_ = 64, F_ = 320, E_ = 128;
constexpr int NCH = 128, CHROWS = B_ / NCH;
constexpr int NBT = B_ / 16;   // 2048 batch tiles of 16

typedef __attribute__((ext_vector_type(8))) __bf16 bf16x8;
typedef __attribute__((ext_vector_type(4))) float f32x4;
union U4 { uint4 u; bf16x8 v; __bf16 b[8]; };

__device__ __forceinline__ float lrelu(float x){ return x >= 0.f ? x : 0.01f*x; }
__device__ __forceinline__ f32x4 mfma16(bf16x8 a, bf16x8 b, f32x4 c){
  return __builtin_amdgcn_mfma_f32_16x16x32_bf16(a, b, c, 0, 0, 0);
}
__device__ __forceinline__ bf16x8 pk8(f32x4 lo, f32x4 hi){
  U4 r;
  r.b[0]=(__bf16)lo[0]; r.b[1]=(__bf16)lo[1]; r.b[2]=(__bf16)lo[2]; r.b[3]=(__bf16)lo[3];
  r.b[4]=(__bf16)hi[0]; r.b[5]=(__bf16)hi[1]; r.b[6]=(__bf16)hi[2]; r.b[7]=(__bf16)hi[3];
  return r.v;
}
__device__ __forceinline__ bf16x8 pk8f(float4 a, float4 b){
  U4 r;
  r.b[0]=(__bf16)a.x; r.b[1]=(__bf16)a.y; r.b[2]=(__bf16)a.z; r.b[3]=(__bf16)a.w;
  r.b[4]=(__bf16)b.x; r.b[5]=(__bf16)b.y; r.b[6]=(__bf16)b.z; r.b[7]=(__bf16)b.w;
  return r.v;
}
__device__ __forceinline__ void gl_lds16(const void* g, void* s){
  __builtin_amdgcn_global_load_lds(
      (const __attribute__((address_space(1))) unsigned int*)g,
      (__attribute__((address_space(3))) unsigned int*)s, 16, 0, 0);
}
template<int N> __device__ __forceinline__ void vmwait(){
  asm volatile("s_waitcnt vmcnt(%0)" :: "n"(N) : "memory");
}
__device__ __forceinline__ void lgkm0(){ asm volatile("s_waitcnt lgkmcnt(0)" ::: "memory"); }
__device__ __forceinline__ void sbar(){ __builtin_amdgcn_s_barrier(); }
__device__ __forceinline__ void schb(){ __builtin_amdgcn_sched_barrier(0); }

// ---------------- Stage 0: BN stats + fused per-row argmax(act) ----------------
__global__ void k_stats_partial(const float* __restrict__ obs,
                                const float* __restrict__ act,
                                float* __restrict__ psum, float* __restrict__ psq,
                                int* __restrict__ ids){
  const int f = threadIdx.x, ch = blockIdx.x, a = blockIdx.y;
  const size_t b0 = (size_t)ch * CHROWS;
  float s = 0.f, q = 0.f;
  if (f < O_){
    const float* p = obs + ((size_t)a*B_ + b0)*O_ + f;
    for (int i = 0; i < CHROWS; ++i){ float x = p[(size_t)i*O_]; s += x; q += x*x; }
  } else {
    const float* p = act + ((size_t)a*B_ + b0)*C_ + (f - O_);
    for (int i = 0; i < CHROWS; ++i){ float x = p[(size_t)i*C_]; s += x; q += x*x; }
  }
  psum[((size_t)a*NCH + ch)*F_ + f] = s;
  psq [((size_t)a*NCH + ch)*F_ + f] = q;
  // argmax for the same 256 rows (act tile is L2-hot from the loop above)
  if (f < CHROWS){
    const float4* ar = (const float4*)(act + ((size_t)a*B_ + b0 + f)*C_);
    float best = -3.4e38f; int bi = 0;
    #pragma unroll 4
    for (int j = 0; j < 16; ++j){
      const float4 v = ar[j];
      const int c0 = j*4;
      if (v.x > best){ best = v.x; bi = c0;   }
      if (v.y > best){ best = v.y; bi = c0+1; }
      if (v.z > best){ best = v.z; bi = c0+2; }
      if (v.w > best){ best = v.w; bi = c0+3; }
    }
    ids[(size_t)a*B_ + b0 + f] = bi;
  }
}

__global__ void k_stats_final(const float* __restrict__ psum, const float* __restrict__ psq,
                              float* __restrict__ zscale, float* __restrict__ zshift){
  const int f = threadIdx.x, a = blockIdx.x;
  float s = 0.f, q = 0.f;
  for (int ch = 0; ch < NCH; ++ch){
    s += psum[((size_t)a*NCH + ch)*F_ + f];
    q += psq [((size_t)a*NCH + ch)*F_ + f];
  }
  const float mean = s * (1.0f / B_);
  float var = q * (1.0f / B_) - mean * mean;
  var = fmaxf(var, 0.0f);
  const float rs = rsqrtf(var + 1e-5f);
  zscale[a*F_ + f] = rs;
  zshift[a*F_ + f] = -mean * rs;
}

// ---- pack weights as MFMA A-fragments; BN folded into Ap + gsb ----
__global__ void k_prep_pack(const float* __restrict__ gW, const float* __restrict__ ggam,
                            const float* __restrict__ sW, const float* __restrict__ sgam,
                            const float* __restrict__ f1W, const float* __restrict__ f2W,
                            const float* __restrict__ Vm, const float* __restrict__ zscale,
                            __bf16* __restrict__ Ap, __bf16* __restrict__ Vp,
                            __bf16* __restrict__ B1p, __bf16* __restrict__ B2p){
  const int a = blockIdx.y;
  const int t0 = blockIdx.x*256 + threadIdx.x;
  constexpr int STR = 32*256;
  for (int i = t0; i < 10*16*64*8; i += STR){
    const int ks = i >> 13, mO = (i>>9)&15, l = (i>>3)&63, e = i&7;
    const int lg = l>>4, fo = mO*16 + (l&15), k = ks*32 + lg*8 + e;
    const float sc = zscale[a*F_ + k];
    float v;
    if (fo < 128) v = gW[(size_t)a*E_*F_ + (size_t)fo*F_ + k] * ggam[a*F_+k] * sc;
    else          v = (k < O_) ? sW[(size_t)a*E_*O_ + (size_t)(fo-128)*O_ + k] * sgam[a*O_+k] * sc : 0.f;
    Ap[(size_t)a*(10*16*64*8) + i] = (__bf16)v;
  }
  for (int i = t0; i < 8*8*64*8; i += STR){
    const int ks = i >> 12, mH = (i>>9)&7, l = (i>>3)&63, e = i&7;
    const int lg = l>>4, h = mH*16 + (l&15);
    const int f = 32*ks + 16*(e>>2) + 4*lg + (e&3);
    B1p[(size_t)a*(8*8*64*8) + i] = (__bf16)f1W[(size_t)a*E_*2*E_ + (size_t)h*2*E_ + f];
  }
  for (int i = t0; i < 4*4*64*8; i += STR){
    const int ks = i >> 11, mC = (i>>9)&3, l = (i>>3)&63, e = i&7;
    const int lg = l>>4, c = mC*16 + (l&15);
    const int f = 32*ks + 16*(e>>2) + 4*lg + (e&3);
    B2p[(size_t)a*(4*4*64*8) + i] = (__bf16)f2W[(size_t)a*C_*E_ + (size_t)c*E_ + f];
  }
  if (a == 0){
    for (int i = t0; i < 4*8*64*8; i += STR){
      const int ks = i >> 12, mV = (i>>9)&7, l = (i>>3)&63, e = i&7;
      const int lg = l>>4, vo = mV*16 + (l&15);
      const int f = 32*ks + 16*(e>>2) + 4*lg + (e&3);
      Vp[i] = (__bf16)Vm[(size_t)vo*E_ + f];
    }
  }
}

__global__ void k_prep_bias(const float* __restrict__ gW, const float* __restrict__ gb,
                            const float* __restrict__ ggam, const float* __restrict__ gbet,
                            const float* __restrict__ sW, const float* __restrict__ sb,
                            const float* __restrict__ sgam, const float* __restrict__ sbet,
                            const float* __restrict__ zshift, float* __restrict__ gsb){
  __shared__ float ww[F_];
  __shared__ float part[2][128];
  const int a = blockIdx.y, t = threadIdx.x;
  const int o = t & 127, h = t >> 7;
  if (blockIdx.x == 0){
    for (int f = t; f < F_; f += 256)
      ww[f] = gbet[a*F_+f] + ggam[a*F_+f]*zshift[a*F_+f];
    __syncthreads();
    float s = 0.f;
    #pragma unroll 4
    for (int f = h*160; f < h*160 + 160; f += 4){
      const float4 wv = *(const float4*)&gW[(size_t)a*E_*F_ + (size_t)o*F_ + f];
      s += wv.x*ww[f] + wv.y*ww[f+1] + wv.z*ww[f+2] + wv.w*ww[f+3];
    }
    part[h][o] = s;
    __syncthreads();
    if (t < 128) gsb[a*256 + t] = gb[a*E_+t] + part[0][t] + part[1][t];
  } else {
    for (int f = t; f < O_; f += 256)
      ww[f] = sbet[a*O_+f] + sgam[a*O_+f]*zshift[a*F_+f];
    __syncthreads();
    float s = 0.f;
    #pragma unroll 4
    for (int f = h*128; f < h*128 + 128; f += 4){
      const float4 wv = *(const float4*)&sW[(size_t)a*E_*O_ + (size_t)o*O_ + f];
      s += wv.x*ww[f] + wv.y*ww[f+1] + wv.z*ww[f+2] + wv.w*ww[f+3];
    }
    part[h][o] = s;
    __syncthreads();
    if (t < 128) gsb[a*256 + 128 + t] = sb[a*E_+t] + part[0][t] + part[1][t];
  }
}

// ---------------- Stage A: square wave-tiles (64 out x 128 batch), bf16 x in LDS ----------------
__global__ __launch_bounds__(256, 2) void k_stageA(
    const float* __restrict__ obs, const float* __restrict__ act,
    const __bf16* __restrict__ Ap, const __bf16* __restrict__ Vp,
    const float* __restrict__ gsb,
    uint4* __restrict__ si_q, uint4* __restrict__ v_q){
  constexpr int BUF = 26624;        // 16 KB weights + 10240 B x (128 rows * 80 B)
  __shared__ __align__(16) char smem[2*BUF];
  const int a = blockIdx.y, t = threadIdx.x;
  const int w = t>>6, l = t&63, l15 = l&15, lg = l>>4;
  const int bt0 = blockIdx.x*8;
  const size_t grow0 = (size_t)a*B_ + (size_t)bt0*16;
  const char* ApA = (const char*)Ap + (size_t)a*163840;
  const int xr = t>>1, kc0 = (t&1)*2;
  const float* obsrow = obs + (grow0 + xr)*O_;
  const float* actrow = act + (grow0 + xr)*C_;

  float4 xA[4], xB[4];

  auto wstage = [&](int ks, char* buf){
    const char* src = ApA + ks*16384;
    #pragma unroll
    for (int i = 0; i < 4; ++i)
      gl_lds16(src + (w*4+i)*1024 + l*16, buf + (w*4+i)*1024);
  };
  auto xload = [&](int ks, float4* d){
    const float* s = (ks < 8) ? (obsrow + ks*32 + kc0*8) : (actrow + (ks-8)*32 + kc0*8);
    d[0] = ((const float4*)s)[0]; d[1] = ((const float4*)s)[1];
    d[2] = ((const float4*)s)[2]; d[3] = ((const float4*)s)[3];
  };
  auto xwrite = [&](char* buf, const float4* d){
    *(bf16x8*)(buf + 16384 + xr*80 + kc0*16)     = pk8f(d[0], d[1]);
    *(bf16x8*)(buf + 16384 + xr*80 + (kc0+1)*16) = pk8f(d[2], d[3]);
  };

  f32x4 acc[4][8] = {};

  // prologue
  wstage(0, smem); schb();
  xload(0, xA);
  vmwait<0>();
  xwrite(smem, xA);
  xload(1, xB);
  lgkm0(); sbar(); schb();

  #pragma unroll
  for (int ks = 0; ks < 10; ++ks){
    char* cur = smem + (ks&1)*BUF;
    char* nxt = smem + ((ks+1)&1)*BUF;
    if (ks+1 < 10){ wstage(ks+1, nxt); schb(); }
    if (ks+2 < 10) xload(ks+2, (ks&1) ? xB : xA);
    {
      const bf16x8* wc = (const bf16x8*)cur;
      const char* xb = cur + 16384;
      bf16x8 bfr[8];
      #pragma unroll
      for (int nt = 0; nt < 8; ++nt)
        bfr[nt] = *(const bf16x8*)(xb + (nt*16 + l15)*80 + lg*16);
      #pragma unroll
      for (int m = 0; m < 4; ++m){
        const bf16x8 af = wc[(w*4+m)*64 + l];
        #pragma unroll
        for (int nt = 0; nt < 8; ++nt)
          acc[m][nt] = mfma16(af, bfr[nt], acc[m][nt]);
      }
    }
    schb();
    if (ks <= 7)      vmwait<4>();
    else if (ks == 8) vmwait<0>();
    if (ks+1 < 10) xwrite(nxt, (ks&1) ? xA : xB);
    if (ks < 9){ lgkm0(); sbar(); schb(); }
  }

  // bias + lrelu; feature = w*64 + m*16 + lg*4 + j
  const float* bE = gsb + a*256 + w*64 + lg*4;
  #pragma unroll
  for (int m = 0; m < 4; ++m){
    const float4 b = *(const float4*)(bE + m*16);
    #pragma unroll
    for (int nt = 0; nt < 8; ++nt){
      acc[m][nt][0] = lrelu(acc[m][nt][0] + b.x);
      acc[m][nt][1] = lrelu(acc[m][nt][1] + b.y);
      acc[m][nt][2] = lrelu(acc[m][nt][2] + b.z);
      acc[m][nt][3] = lrelu(acc[m][nt][3] + b.w);
    }
  }
  sbar();   // all k-loop LDS reads done; smem reusable for e-frags

  if (w < 2){
    // e-frags -> LDS, pi layout: elem e <-> feature 32*kv + 16(e>>2)+4lg+(e&3)
    #pragma unroll
    for (int jp = 0; jp < 2; ++jp){
      const int kv = 2*w + jp;
      #pragma unroll
      for (int nt = 0; nt < 8; ++nt)
        *(bf16x8*)(smem + ((kv*8 + nt)*64 + l)*16) = pk8(acc[2*jp][nt], acc[2*jp+1][nt]);
    }
  } else {
    #pragma unroll
    for (int jp = 0; jp < 2; ++jp){
      const int j = 2*(w-2) + jp;
      #pragma unroll
      for (int nt = 0; nt < 8; ++nt){
        U4 u; u.v = pk8(acc[2*jp][nt], acc[2*jp+1][nt]);
        si_q[(((size_t)a*NBT + bt0 + nt)*4 + j)*64 + l] = u.u;
      }
    }
  }
  lgkm0(); sbar(); schb();

  // v-GEMM: v = lrelu(e @ V^T); wave w owns v-outputs [w*32, w*32+32)
  const uint4* Vq = (const uint4*)Vp;
  f32x4 accv[2][8] = {};
  #pragma unroll
  for (int kv = 0; kv < 4; ++kv){
    U4 a0, a1;
    a0.u = Vq[(kv*8 + w*2 + 0)*64 + l];
    a1.u = Vq[(kv*8 + w*2 + 1)*64 + l];
    bf16x8 bv[8];
    #pragma unroll
    for (int nt = 0; nt < 8; ++nt)
      bv[nt] = *(const bf16x8*)(smem + ((kv*8 + nt)*64 + l)*16);
    #pragma unroll
    for (int nt = 0; nt < 8; ++nt){
      accv[0][nt] = mfma16(a0.v, bv[nt], accv[0][nt]);
      accv[1][nt] = mfma16(a1.v, bv[nt], accv[1][nt]);
    }
  }
  #pragma unroll
  for (int nt = 0; nt < 8; ++nt){
    f32x4 lo, hi;
    #pragma unroll
    for (int e = 0; e < 4; ++e){ lo[e] = lrelu(accv[0][nt][e]); hi[e] = lrelu(accv[1][nt][e]); }
    U4 u; u.v = pk8(lo, hi);
    v_q[(((size_t)a*NBT + bt0 + nt)*4 + w)*64 + l] = u.u;
  }
}

// ---------------- vsum over agents (bf16 frags) ----------------
__global__ void k_vsum(const uint4* __restrict__ v_q, uint4* __restrict__ vsum_q){
  const size_t i = (size_t)blockIdx.x*256 + threadIdx.x;
  const size_t per_a = (size_t)NBT*4*64;
  float s[8] = {0,0,0,0,0,0,0,0};
  #pragma unroll
  for (int aa = 0; aa < 8; ++aa){
    U4 u; u.u = v_q[aa*per_a + i];
    #pragma unroll
    for (int e = 0; e < 8; ++e) s[e] += (float)u.b[e];
  }
  U4 o;
  #pragma unroll
  for (int e = 0; e < 8; ++e) o.b[e] = (__bf16)s[e];
  vsum_q[i] = o.u;
}

// ---------------- Stage C: x = vsum - v | si -> h -> q -> gather ----------------
__global__ __launch_bounds__(256, 2) void k_stageC(
    const uint4* __restrict__ v_q, const uint4* __restrict__ si_q,
    const uint4* __restrict__ vsum_q,
    const __bf16* __restrict__ B1p, const __bf16* __restrict__ B2p,
    const float* __restrict__ f1b, const float* __restrict__ f2b,
    const int* __restrict__ ids, float* __restrict__ out){
  __shared__ __align__(16) char wsm[2*8192];
  __shared__ float qs[4][64][17];
  const int a = blockIdx.y, t = threadIdx.x;
  const int w = t>>6, l = t&63, l15 = l&15, lg = l>>4;
  const int btw = blockIdx.x*16 + w*4;   // wave's 4 batch tiles (64 rows)
  const char* B1A = (const char*)B1p + (size_t)a*65536;
  const size_t vbase = (size_t)a*NBT*4*64;

  uint4 qA[4], qB[4], sA[4], sB[4];

  auto wstage = [&](int ks, char* dst){
    const char* src = B1A + ks*8192;
    #pragma unroll
    for (int i = 0; i < 2; ++i)
      gl_lds16(src + (w*2+i)*1024 + l*16, dst + (w*2+i)*1024);
  };
  auto bload = [&](int ks, uint4* qv, uint4* sv){
    if (ks < 4){
      #pragma unroll
      for (int nt = 0; nt < 4; ++nt){
        const size_t idx = ((size_t)(btw+nt)*4 + ks)*64 + l;
        qv[nt] = v_q[vbase + idx];
        sv[nt] = vsum_q[idx];
      }
    } else {
      #pragma unroll
      for (int nt = 0; nt < 4; ++nt)
        qv[nt] = si_q[vbase + ((size_t)(btw+nt)*4 + (ks-4))*64 + l];
    }
  };
  auto bmake = [&](int ks, const uint4* qv, const uint4* sv, bf16x8* bf){
    if (ks < 4){
      #pragma unroll
      for (int nt = 0; nt < 4; ++nt){
        U4 s, v; s.u = sv[nt]; v.u = qv[nt];
        f32x4 lo, hi;
        #pragma unroll
        for (int e = 0; e < 4; ++e){
          lo[e] = (float)s.b[e]   - (float)v.b[e];
          hi[e] = (float)s.b[e+4] - (float)v.b[e+4];
        }
        bf[nt] = pk8(lo, hi);
      }
    } else {
      #pragma unroll
      for (int nt = 0; nt < 4; ++nt){ U4 u; u.u = qv[nt]; bf[nt] = u.v; }
    }
  };

  f32x4 hacc[8][4] = {};
  wstage(0, wsm); schb();
  bload(0, qA, sA); schb();
  bload(1, qB, sB);
  vmwait<8>();
  sbar(); schb();

  #pragma unroll
  for (int ks = 0; ks < 8; ++ks){
    bf16x8 bf[4];
    bmake(ks, (ks&1) ? qB : qA, (ks&1) ? sB : sA, bf);
    if (ks+1 < 8){ wstage(ks+1, wsm + ((ks+1)&1)*8192); schb(); }
    if (ks+2 < 8) bload(ks+2, (ks&1) ? qB : qA, (ks&1) ? sB : sA);
    {
      const bf16x8* wc = (const bf16x8*)(wsm + (ks&1)*8192);
      #pragma unroll
      for (int m = 0; m < 8; ++m){
        const bf16x8 af = wc[m*64 + l];
        #pragma unroll
        for (int nt = 0; nt < 4; ++nt)
          hacc[m][nt] = mfma16(af, bf[nt], hacc[m][nt]);
      }
    }
    schb();
    if (ks <= 1)      vmwait<8>();
    else if (ks <= 5) vmwait<4>();
    else if (ks == 6) vmwait<0>();
    if (ks < 7){ sbar(); schb(); }
  }

  // h bias + lrelu, pack to q B-frags (pi map, all lane-local)
  bf16x8 hb[4][4];
  const float* bH = f1b + a*E_ + lg*4;
  #pragma unroll
  for (int kq = 0; kq < 4; ++kq){
    const float4 b0v = *(const float4*)(bH + (2*kq)*16);
    const float4 b1v = *(const float4*)(bH + (2*kq+1)*16);
    #pragma unroll
    for (int nt = 0; nt < 4; ++nt){
      f32x4 lo, hi;
      lo[0]=lrelu(hacc[2*kq][nt][0]+b0v.x); lo[1]=lrelu(hacc[2*kq][nt][1]+b0v.y);
      lo[2]=lrelu(hacc[2*kq][nt][2]+b0v.z); lo[3]=lrelu(hacc[2*kq][nt][3]+b0v.w);
      hi[0]=lrelu(hacc[2*kq+1][nt][0]+b1v.x); hi[1]=lrelu(hacc[2*kq+1][nt][1]+b1v.y);
      hi[2]=lrelu(hacc[2*kq+1][nt][2]+b1v.z); hi[3]=lrelu(hacc[2*kq+1][nt][3]+b1v.w);
      hb[kq][nt] = pk8(lo, hi);
    }
  }
  // q-GEMM
  const uint4* A2q = (const uint4*)(B2p + (size_t)a*(4*4*64*8));
  f32x4 accq[4][4] = {};
  #pragma unroll
  for (int kq = 0; kq < 4; ++kq){
    #pragma unroll
    for (int mC = 0; mC < 4; ++mC){
      U4 af; af.u = A2q[(kq*4 + mC)*64 + l];
      #pragma unroll
      for (int nt = 0; nt < 4; ++nt)
        accq[mC][nt] = mfma16(af.v, hb[kq][nt], accq[mC][nt]);
    }
  }
  const float* bQ = f2b + a*C_ + lg*4;
  float4 qb[4];
  #pragma unroll
  for (int mC = 0; mC < 4; ++mC) qb[mC] = *(const float4*)(bQ + mC*16);
  #pragma unroll
  for (int nt = 0; nt < 4; ++nt){
    #pragma unroll
    for (int mC = 0; mC < 4; ++mC){
      qs[w][mC*16 + lg*4 + 0][l15] = accq[mC][nt][0] + qb[mC].x;
      qs[w][mC*16 + lg*4 + 1][l15] = accq[mC][nt][1] + qb[mC].y;
      qs[w][mC*16 + lg*4 + 2][l15] = accq[mC][nt][2] + qb[mC].z;
      qs[w][mC*16 + lg*4 + 3][l15] = accq[mC][nt][3] + qb[mC].w;
    }
    lgkm0();
    if (l < 16){
      const size_t row = (size_t)(btw + nt)*16 + l;
      const int id = ids[(size_t)a*B_ + row];
      out[(size_t)a*B_ + row] = qs[w][id][l];
    }
    lgkm0();
  }
}

extern "C" void kernel_launch(void* const* d_in, const int* in_sizes, int n_in,
                              void* d_out, int out_size, void* d_ws, size_t ws_size,
                              hipStream_t stream) {
  const float* obs  = (const float*)d_in[0];
  const float* act  = (const float*)d_in[1];
  const float* ggam = (const float*)d_in[2];
  const float* gbet = (const float*)d_in[3];
  const float* gW   = (const float*)d_in[4];
  const float* gb   = (const float*)d_in[5];
  const float* sgam = (const float*)d_in[6];
  const float* sbet = (const float*)d_in[7];
  const float* sW   = (const float*)d_in[8];
  const float* sb   = (const float*)d_in[9];
  const float* f1W  = (const float*)d_in[10];
  const float* f1b  = (const float*)d_in[11];
  const float* f2W  = (const float*)d_in[12];
  const float* f2b  = (const float*)d_in[13];
  // d_in[14]=Wq, d_in[15]=Wk dead (softmax over length-1 axis == 1)
  const float* Vm   = (const float*)d_in[16];
  float* out = (float*)d_out;

  char* base = (char*)d_ws; size_t off = 0;
  auto alloc = [&](size_t bytes) -> void* {
    off = (off + 255) & ~(size_t)255; void* p = base + off; off += bytes; return p;
  };
  float* psum    = (float*)alloc((size_t)A_*NCH*F_*4);
  float* psq     = (float*)alloc((size_t)A_*NCH*F_*4);
  float* zscale  = (float*)alloc((size_t)A_*F_*4);
  float* zshift  = (float*)alloc((size_t)A_*F_*4);
  float* gsb     = (float*)alloc((size_t)A_*256*4);
  __bf16* Ap     = (__bf16*)alloc((size_t)A_*10*16*64*8*2);
  __bf16* Vp     = (__bf16*)alloc((size_t)4*8*64*8*2);
  __bf16* B1p    = (__bf16*)alloc((size_t)A_*8*8*64*8*2);
  __bf16* B2p    = (__bf16*)alloc((size_t)A_*4*4*64*8*2);
  uint4* si_q    = (uint4*)alloc((size_t)A_*NBT*4*64*16);
  uint4* v_q     = (uint4*)alloc((size_t)A_*NBT*4*64*16);
  uint4* vsum_q  = (uint4*)alloc((size_t)NBT*4*64*16);
  int*   ids     = (int*)alloc((size_t)A_*B_*4);
  (void)ws_size; (void)in_sizes; (void)n_in; (void)out_size;

  k_stats_partial<<<dim3(NCH, A_), 320, 0, stream>>>(obs, act, psum, psq, ids);
  k_stats_final<<<A_, F_, 0, stream>>>(psum, psq, zscale, zshift);
  k_prep_pack<<<dim3(32, A_), 256, 0, stream>>>(gW, ggam, sW, sgam, f1W, f2W, Vm,
                                                zscale, Ap, Vp, B1p, B2p);
  k_prep_bias<<<dim3(2, A_), 256, 0, stream>>>(gW, gb, ggam, gbet, sW, sb, sgam, sbet,
                                               zshift, gsb);
  k_stageA<<<dim3(NBT/8, A_), 256, 0, stream>>>(obs, act, Ap, Vp, gsb, si_q, v_q);
  k_vsum<<<(NBT*4*64)/256, 256, 0, stream>>>(v_q, vsum_q);
  k_stageC<<<dim3(NBT/16, A_), 256, 0, stream>>>(v_q, si_q, vsum_q, B1p, B2p,
                                                 f1b, f2b, ids, out);
}